// Round 5
// baseline (287.164 us; speedup 1.0000x reference)
//
#include <hip/hip_runtime.h>
#include <hip/hip_bf16.h>
#include <stdint.h>

typedef __bf16 bf16_t;
typedef __bf16 bf16x8 __attribute__((ext_vector_type(8)));
typedef float  f32x4  __attribute__((ext_vector_type(4)));

// async 16B global -> LDS (global_load_lds_dwordx4).
__device__ __forceinline__ void async_copy16(const bf16_t* g, bf16_t* l) {
    __builtin_amdgcn_global_load_lds(
        (const __attribute__((address_space(1))) unsigned int*)(uintptr_t)g,
        (__attribute__((address_space(3))) unsigned int*)(uintptr_t)l,
        16, 0, 0);
}

// Counted vmcnt wait. NO memory clobber: a "memory" clobber makes the asm an
// opaque memory op and SIInsertWaitcnts prepends s_waitcnt vmcnt(0) to it,
// which silently degrades the whole schedule to drain-per-phase (round-1 bug).
template<int N> __device__ __forceinline__ void vmw() {
    if constexpr (N == 0)      asm volatile("s_waitcnt vmcnt(0)");
    else if constexpr (N == 5) asm volatile("s_waitcnt vmcnt(5)");
    else if constexpr (N == 6) asm volatile("s_waitcnt vmcnt(6)");
}
#define BARR() __builtin_amdgcn_s_barrier()

// ---------------------------------------------------------------------------
// BMx256 8-phase NT GEMM, bf16 in, fp32 acc: C[m,n] = op(sum_k A[m,k]*B[n,k]+bias)
// 512 thr = 8 waves (2 row-groups x 4 col-groups). Phase = one (BM/2)x128
// C-region over a K=64 tile: per wave (BM/64) x 2 frags of 16x16 x 2 ksteps ->
// 4*(BM/64) x mfma_f32_16x16x32_bf16 (16 for BM=256, 8 for BM=128).
//
// NOTE fragment shape: 16x16 (l15-row reads), NOT 32x32 (r32-row reads).
// Empirical across rounds 0/1/2: r32-pattern ds_read_b128 = 4.19M bank-conflict
// cycles/dispatch; l15-pattern = 0.  Same slot-XOR swizzle in both.
//
// LDS: 2 buf x (A[BM][64] + B[256][64]) bf16 = 128 KiB (BM=256) / 96 KiB (128).
//
// Stage ledger (1 half-tile per phase; T = 2i; A-half = LA loads, B-half = 2):
//   p1: A1(T+1)->buf1   p2: A0(T+2)->buf0   p3: B0(T+2)->buf0  p4: B1(T+2)->buf0
//   p5: A1(T+2)->buf0   p6: A0(T+3)->buf1   p7: B0(T+3)->buf1  p8: B1(T+3)->buf1
// Reads: p1:{A0,B0} p2:{B1} p3:{A1} p4:{} of buf0/T; p5..p8 same of buf1/T+1.
// vmcnt(4+LA) after MMA at p4 and p8 only (3 stages in flight):
//   p4 wait covers <= p1 -> buf1 tile 2i+1 fully landed (prev p6,p7,p8 + p1).
//   p8 wait covers <= p5 -> buf0 tile 2i+2 fully landed (p2,p3,p4,p5).
// Write-safety: every stage overwrites a half-tile whose last ds_read was >=1
// barrier earlier, and those reads are consumed by same-phase MFMAs (dataflow
// lgkmcnt) before that barrier.  Last iter: skip p2..p8 stages, p4 -> vmcnt(0).
// ---------------------------------------------------------------------------

#define STAGEA(buf, h, kt) do {                                                   \
    _Pragma("unroll") for (int j = 0; j < LA; j++)                                \
        async_copy16(ApM + (long)(h)*(BM/2)*K + (long)(kt)*64 + offA[j],          \
                     (bf16_t*)(lds + (buf)*BUF + (h)*HBYTES + dstA[j]));          \
} while (0)

#define STAGEB(buf, h, kt) do {                                                   \
    _Pragma("unroll") for (int j = 0; j < 2; j++)                                 \
        async_copy16(BpN + (long)(h)*128*K + (long)(kt)*64 + offB[j],             \
                     (bf16_t*)(lds + (buf)*BUF + ABYTES + (h)*16384 + dstB[j]));  \
} while (0)

// 16x16x32 frags: row/col = l15, k = ks*32 + l4*8 + 0..7 -> 16B slot ks*4+l4,
// stored (and read) at slot ^ (row&7): same involution on both sides (stage
// pre-swizzles the GLOBAL source, LDS dest stays linear).
#define LOADA(buf, hA) do {                                                       \
    _Pragma("unroll") for (int m = 0; m < MF; m++)                                \
    _Pragma("unroll") for (int ks = 0; ks < 2; ks++) {                            \
        const int R = (hA)*(BM/2) + sr*(BM/4) + m*16 + l15;                       \
        afr[m][ks] = *(const bf16x8*)(lds + (buf)*BUF + R*128                     \
                                      + (((ks*4 + l4) ^ (l15 & 7)) << 4));        \
    } } while (0)

#define LOADB(buf, hB) do {                                                       \
    _Pragma("unroll") for (int n = 0; n < 2; n++)                                 \
    _Pragma("unroll") for (int ks = 0; ks < 2; ks++) {                            \
        const int Cc = (hB)*128 + sc*32 + n*16 + l15;                             \
        bfr[hB][n][ks] = *(const bf16x8*)(lds + (buf)*BUF + ABYTES + Cc*128       \
                                          + (((ks*4 + l4) ^ (l15 & 7)) << 4));    \
    } } while (0)

#define MMA(hA, hB) do {                                                          \
    __builtin_amdgcn_s_setprio(1);                                                \
    _Pragma("unroll") for (int m = 0; m < MF; m++)                                \
    _Pragma("unroll") for (int n = 0; n < 2; n++)                                 \
    _Pragma("unroll") for (int ks = 0; ks < 2; ks++)                              \
        acc[hA][hB][m][n] = __builtin_amdgcn_mfma_f32_16x16x32_bf16(              \
            afr[m][ks], bfr[hB][n][ks], acc[hA][hB][m][n], 0, 0, 0);              \
    __builtin_amdgcn_s_setprio(0);                                                \
} while (0)

// BIAS_MODE: 0=none, 1=bias[col], 2=bias[row].  BIAS_SPLIT: bias1 when bz>0.
template<int BM, bool OUT_F32, bool RELU, int BIAS_MODE, bool BIAS_SPLIT>
__global__ __launch_bounds__(512, 2)
void gemm256(const bf16_t* __restrict__ A, const bf16_t* __restrict__ B,
             const float* __restrict__ bias0, const float* __restrict__ bias1,
             void* __restrict__ Cp,
             int K, int ldc, long sAb, long sBb, long sCb)
{
    constexpr int MF     = BM / 64;           // 16-row m-frags per wave per phase
    constexpr int LA     = BM / 128;          // loads per thread per A half-tile
    constexpr int VMN    = 4 + LA;            // steady-state vmcnt
    constexpr int ABYTES = BM * 128;          // A tile bytes (BM x 64 bf16)
    constexpr int HBYTES = ABYTES / 2;
    constexpr int BUF    = ABYTES + 32768;

    __shared__ char lds[2 * BUF];

    // bijective XCD-chunk swizzle (all grids here are 256 wg, %8 == 0)
    const int gx = gridDim.x, gy = gridDim.y;
    const int tot = gx * gy * gridDim.z;
    const int lin = (blockIdx.z * gy + blockIdx.y) * gx + blockIdx.x;
    const int q8  = tot >> 3;
    const int wg  = (lin & 7) * q8 + (lin >> 3);
    const int bz  = wg / (gx * gy);
    const int r2  = wg - bz * gx * gy;
    const int by  = r2 / gx;
    const int bx  = r2 - by * gx;
    const int blockM = by * BM;
    const int blockN = bx * 256;

    const int t    = threadIdx.x;
    const int lane = t & 63;
    const int wave = t >> 6;
    const int sr   = wave >> 2;         // 0..1 row group
    const int sc   = wave & 3;          // 0..3 col group
    const int l15  = lane & 15;
    const int l4   = lane >> 4;         // 0..3 k-slot group

    const bf16_t* ApM = A + sAb * (long)bz + (long)blockM * K;
    const bf16_t* BpN = B + sBb * (long)bz + (long)blockN * K;

    // staging constants: chunk c of a half-tile; row=c>>3, slot=c&7; global
    // source pre-swizzled (slot ^ row&7), LDS dest linear (c*16).
    long offA[LA]; uint32_t dstA[LA];
    #pragma unroll
    for (int j = 0; j < LA; j++) {
        const int c = t + j * 512, r = c >> 3, s = c & 7;
        offA[j] = (long)r * K + ((s ^ (r & 7)) * 8);
        dstA[j] = (uint32_t)c * 16;
    }
    long offB[2]; uint32_t dstB[2];
    #pragma unroll
    for (int j = 0; j < 2; j++) {
        const int c = t + j * 512, r = c >> 3, s = c & 7;
        offB[j] = (long)r * K + ((s ^ (r & 7)) * 8);
        dstB[j] = (uint32_t)c * 16;
    }

    f32x4  acc[2][2][MF][2] = {};
    bf16x8 afr[MF][2];
    bf16x8 bfr[2][2][2];

    const int NT = K >> 6;
    const int NI = NT >> 1;

    // prologue: buf0 tile0 {A0,B0,B1,A1}; buf1 tile1 {A0,B0,B1}.
    // vmcnt(VMN) leaves exactly the 3 tile-1 stages in flight -> tile0 landed.
    STAGEA(0, 0, 0); STAGEB(0, 0, 0); STAGEB(0, 1, 0); STAGEA(0, 1, 0);
    STAGEA(1, 0, 1); STAGEB(1, 0, 1); STAGEB(1, 1, 1);
    vmw<VMN>();
    BARR();

    for (int i = 0; i < NI; ++i) {
        const int  T  = 2 * i;
        const bool nl = (i < NI - 1);

        // p1: (buf0, A0, B0)
        LOADA(0, 0); LOADB(0, 0);
        STAGEA(1, 1, T + 1);
        BARR();
        MMA(0, 0);
        BARR();
        // p2: (buf0, A0, B1) — afr reused
        LOADB(0, 1);
        if (nl) STAGEA(0, 0, T + 2);
        BARR();
        MMA(0, 1);
        BARR();
        // p3: (buf0, A1, B0) — bfr[0] reused
        LOADA(0, 1);
        if (nl) STAGEB(0, 0, T + 2);
        BARR();
        MMA(1, 0);
        BARR();
        // p4: (buf0, A1, B1) — all frags reused; K-tile wait
        if (nl) STAGEB(0, 1, T + 2);
        BARR();
        MMA(1, 1);
        if (nl) vmw<VMN>(); else vmw<0>();
        BARR();
        // p5: (buf1, A0, B0)
        LOADA(1, 0); LOADB(1, 0);
        if (nl) STAGEA(0, 1, T + 2);
        BARR();
        MMA(0, 0);
        BARR();
        // p6: (buf1, A0, B1)
        LOADB(1, 1);
        if (nl) STAGEA(1, 0, T + 3);
        BARR();
        MMA(0, 1);
        BARR();
        // p7: (buf1, A1, B0)
        LOADA(1, 1);
        if (nl) STAGEB(1, 0, T + 3);
        BARR();
        MMA(1, 0);
        BARR();
        // p8: (buf1, A1, B1); K-tile wait
        if (nl) STAGEB(1, 1, T + 3);
        BARR();
        MMA(1, 1);
        if (nl) vmw<VMN>();
        BARR();
    }

    // epilogue: 16x16 C/D layout: col = lane&15, row = (lane>>4)*4 + reg
    float*  Cf = (float*) Cp + sCb * (long)bz;
    bf16_t* Ch = (bf16_t*)Cp + sCb * (long)bz;
    const float* bias = (BIAS_SPLIT && bz) ? bias1 : bias0;
    #pragma unroll
    for (int hA = 0; hA < 2; hA++)
    #pragma unroll
    for (int hB = 0; hB < 2; hB++)
    #pragma unroll
    for (int m = 0; m < MF; m++)
    #pragma unroll
    for (int n = 0; n < 2; n++) {
        const int gcol = blockN + hB * 128 + sc * 32 + n * 16 + l15;
        float bc = 0.f;
        if (BIAS_MODE == 1) bc = bias[gcol];
        #pragma unroll
        for (int reg = 0; reg < 4; reg++) {
            const int grow = blockM + hA * (BM / 2) + sr * (BM / 4) + m * 16
                           + l4 * 4 + reg;
            float vv = acc[hA][hB][m][n][reg];
            if (BIAS_MODE == 1) vv += bc;
            if (BIAS_MODE == 2) vv += bias[grow];
            if (RELU) vv = fmaxf(vv, 0.f);
            if (OUT_F32) Cf[(long)grow * ldc + gcol] = vv;
            else         Ch[(long)grow * ldc + gcol] = (bf16_t)vv;
        }
    }
}

// fp32 -> bf16 cast of q,k,v,Wq,Wk,Wv into workspace.
// Fully-coalesced m13 copy shape: ONE float4 per lane per iteration (16 B/lane
// reads, lane-contiguous -> 1 KB/wave/instr; 8 B/lane bf16 stores, contiguous).
// Rounds 2/3 used thread-contiguous 32/64-byte chunks: lanes strided 32/64 B
// within each load instr -> 2x/4x cacheline-transaction inflation -> stuck at
// ~2.3 TB/s HBM (45/48 us).  All range sizes are powers of two: q/k/v = 2^21
// float4s each, W = 2^18 each; 7077888 units = exactly 8 iters x 884736 thr.
__global__ __launch_bounds__(256)
void cast_all_kernel(const float* __restrict__ q, const float* __restrict__ k,
                     const float* __restrict__ v, const float* __restrict__ Wq,
                     const float* __restrict__ Wk, const float* __restrict__ Wv,
                     bf16_t* __restrict__ ws)
{
    const int U_BIG   = 2097152;                // 2^21 float4s per q/k/v tensor
    const int U_SMALL = 262144;                 // 2^18 float4s per weight
    const int U_TOT   = 3 * U_BIG + 3 * U_SMALL;
    const int stride  = gridDim.x * blockDim.x;
    for (int u = blockIdx.x * blockDim.x + threadIdx.x; u < U_TOT; u += stride) {
        const float* src; bf16_t* dst;
        if (u < 3 * U_BIG) {
            const int s   = u >> 21;
            const long o4 = (long)(u & (U_BIG - 1)) << 2;   // element offset
            src = (s == 0 ? q : s == 1 ? k : v) + o4;
            dst = ws + (long)s * 8388608 + o4;
        } else {
            const int u2  = u - 3 * U_BIG;
            const int s   = u2 >> 18;
            const long o4 = (long)(u2 & (U_SMALL - 1)) << 2;
            src = (s == 0 ? Wq : s == 1 ? Wk : Wv) + o4;
            dst = ws + 25165824L + (long)s * 1048576 + o4;
        }
        float4 a = *(const float4*)src;
        alignas(8) bf16_t o[4];
        o[0] = (bf16_t)a.x; o[1] = (bf16_t)a.y;
        o[2] = (bf16_t)a.z; o[3] = (bf16_t)a.w;
        *(uint2*)dst = *(const uint2*)o;
    }
}

extern "C" void kernel_launch(void* const* d_in, const int* in_sizes, int n_in,
                              void* d_out, int out_size, void* d_ws, size_t ws_size,
                              hipStream_t stream)
{
    const float* q   = (const float*)d_in[0];
    const float* k   = (const float*)d_in[1];
    const float* v   = (const float*)d_in[2];
    const float* Wq  = (const float*)d_in[3];
    const float* bq  = (const float*)d_in[4];
    const float* Wk  = (const float*)d_in[5];
    const float* bk  = (const float*)d_in[6];
    const float* Wv  = (const float*)d_in[7];
    const float* bv  = (const float*)d_in[8];

    const int S = 2048, D = 1024;

    // workspace (bf16 element offsets):
    //   qb 0, kb 8388608, vb 16777216 (dead after their GEMM; Sc aliases qb+kb)
    //   Wqb 25165824, Wkb 26214400, Wvb 27262976
    //   Qp 28311552, Kp 36700160, VpT 45088768   (total ~107 MB)
    bf16_t* ws  = (bf16_t*)d_ws;
    bf16_t* qb  = ws;
    bf16_t* vb  = ws + 16777216L;
    bf16_t* Wqb = ws + 25165824L;
    bf16_t* Wvb = ws + 27262976L;
    bf16_t* Qp  = ws + 28311552L;
    bf16_t* VpT = ws + 45088768L;
    bf16_t* Sc  = ws;              // aliases qb+kb (both dead by step 4)

    cast_all_kernel<<<dim3(3456), dim3(256), 0, stream>>>(q, k, v, Wq, Wk, Wv, ws);

    dim3 blk(512);

    // Q and K projections fused via grid.z (qb/kb, Wqb/Wkb, Qp/Kp contiguous):
    // [M=8192, N=1024, K=1024] x2 -> grid (4,32,2) = 256 wg
    gemm256<256, false, false, 1, true><<<dim3(4, 32, 2), blk, 0, stream>>>(
        qb, Wqb, bq, bk, Qp, D, D, 8388608L, 1048576L, 8388608L);

    // VpT[b] = (v_b @ Wv^T + bv)^T : A=Wvb [1024,1024], B=vb_b [2048,1024],
    // row bias.  BM=128 -> grid (8,8,4) = 256 wg
    gemm256<128, false, false, 2, false><<<dim3(8, 8, 4), blk, 0, stream>>>(
        Wvb, vb, bv, nullptr, VpT, D, S, 0L, (long)S * D, (long)D * S);

    // Sc[b] = relu(Qp_b @ Kp_b^T)  [2048x2048, K=1024], bf16 out -> (8,8,4)=256 wg
    gemm256<256, false, true, 0, false><<<dim3(8, 8, 4), blk, 0, stream>>>(
        Qp, Qp + 8388608L, nullptr, nullptr, Sc, D, S,
        (long)S * D, (long)S * D, (long)S * S);

    // out[b] = Sc_b @ VpT_b^T  [2048x1024, K=2048], fp32 out.
    // BM=128 -> grid (4,16,4) = 256 wg
    gemm256<128, true, false, 0, false><<<dim3(4, 16, 4), blk, 0, stream>>>(
        Sc, VpT, nullptr, nullptr, d_out, S, D,
        (long)S * S, (long)D * S, (long)S * D);
}

// Round 9
// 284.985 us; speedup vs baseline: 1.0076x; 1.0076x over previous
//
#include <hip/hip_runtime.h>
#include <hip/hip_bf16.h>
#include <stdint.h>

typedef __bf16 bf16_t;
typedef __bf16 bf16x8 __attribute__((ext_vector_type(8)));
typedef float  f32x4  __attribute__((ext_vector_type(4)));

// async 16B global -> LDS (global_load_lds_dwordx4).
__device__ __forceinline__ void async_copy16(const bf16_t* g, bf16_t* l) {
    __builtin_amdgcn_global_load_lds(
        (const __attribute__((address_space(1))) unsigned int*)(uintptr_t)g,
        (__attribute__((address_space(3))) unsigned int*)(uintptr_t)l,
        16, 0, 0);
}

// Counted vmcnt wait. NO memory clobber: a "memory" clobber makes the asm an
// opaque memory op and SIInsertWaitcnts prepends s_waitcnt vmcnt(0) to it,
// which silently degrades the whole schedule to drain-per-phase (round-1 bug).
template<int N> __device__ __forceinline__ void vmw() {
    if constexpr (N == 0)      asm volatile("s_waitcnt vmcnt(0)");
    else if constexpr (N == 5) asm volatile("s_waitcnt vmcnt(5)");
    else if constexpr (N == 6) asm volatile("s_waitcnt vmcnt(6)");
}
#define BARR() __builtin_amdgcn_s_barrier()

// ---------------------------------------------------------------------------
// BMx256 8-phase NT GEMM, bf16 in, fp32 acc: C[m,n] = op(sum_k A[m,k]*B[n,k]+bias)
// 512 thr = 8 waves (2 row-groups x 4 col-groups). Phase = one (BM/2)x128
// C-region over a K=64 tile: per wave (BM/64) x 2 frags of 16x16 x 2 ksteps ->
// 4*(BM/64) x mfma_f32_16x16x32_bf16 (16 for BM=256, 8 for BM=128).
//
// NOTE fragment shape: 16x16 (l15-row reads), NOT 32x32 (r32-row reads).
// Empirical across rounds 0/1/2: r32-pattern ds_read_b128 = 4.19M bank-conflict
// cycles/dispatch; l15-pattern = 0.  Same slot-XOR swizzle in both.
//
// LDS: 2 buf x (A[BM][64] + B[256][64]) bf16 = 128 KiB (BM=256) / 96 KiB (128).
//
// Stage ledger (1 half-tile per phase; T = 2i; A-half = LA loads, B-half = 2):
//   p1: A1(T+1)->buf1   p2: A0(T+2)->buf0   p3: B0(T+2)->buf0  p4: B1(T+2)->buf0
//   p5: A1(T+2)->buf0   p6: A0(T+3)->buf1   p7: B0(T+3)->buf1  p8: B1(T+3)->buf1
// Reads: p1:{A0,B0} p2:{B1} p3:{A1} p4:{} of buf0/T; p5..p8 same of buf1/T+1.
// vmcnt(4+LA) after MMA at p4 and p8 only (3 stages in flight):
//   p4 wait covers <= p1 -> buf1 tile 2i+1 fully landed (prev p6,p7,p8 + p1).
//   p8 wait covers <= p5 -> buf0 tile 2i+2 fully landed (p2,p3,p4,p5).
// Write-safety: every stage overwrites a half-tile whose last ds_read was >=1
// barrier earlier, and those reads are consumed by same-phase MFMAs (dataflow
// lgkmcnt) before that barrier.  Last iter: skip p2..p8 stages, p4 -> vmcnt(0).
// ---------------------------------------------------------------------------

#define STAGEA(buf, h, kt) do {                                                   \
    _Pragma("unroll") for (int j = 0; j < LA; j++)                                \
        async_copy16(ApM + (long)(h)*(BM/2)*K + (long)(kt)*64 + offA[j],          \
                     (bf16_t*)(lds + (buf)*BUF + (h)*HBYTES + dstA[j]));          \
} while (0)

#define STAGEB(buf, h, kt) do {                                                   \
    _Pragma("unroll") for (int j = 0; j < 2; j++)                                 \
        async_copy16(BpN + (long)(h)*128*K + (long)(kt)*64 + offB[j],             \
                     (bf16_t*)(lds + (buf)*BUF + ABYTES + (h)*16384 + dstB[j]));  \
} while (0)

// 16x16x32 frags: row/col = l15, k = ks*32 + l4*8 + 0..7 -> 16B slot ks*4+l4,
// stored (and read) at slot ^ (row&7): same involution on both sides (stage
// pre-swizzles the GLOBAL source, LDS dest stays linear).
#define LOADA(buf, hA) do {                                                       \
    _Pragma("unroll") for (int m = 0; m < MF; m++)                                \
    _Pragma("unroll") for (int ks = 0; ks < 2; ks++) {                            \
        const int R = (hA)*(BM/2) + sr*(BM/4) + m*16 + l15;                       \
        afr[m][ks] = *(const bf16x8*)(lds + (buf)*BUF + R*128                     \
                                      + (((ks*4 + l4) ^ (l15 & 7)) << 4));        \
    } } while (0)

#define LOADB(buf, hB) do {                                                       \
    _Pragma("unroll") for (int n = 0; n < 2; n++)                                 \
    _Pragma("unroll") for (int ks = 0; ks < 2; ks++) {                            \
        const int Cc = (hB)*128 + sc*32 + n*16 + l15;                             \
        bfr[hB][n][ks] = *(const bf16x8*)(lds + (buf)*BUF + ABYTES + Cc*128       \
                                          + (((ks*4 + l4) ^ (l15 & 7)) << 4));    \
    } } while (0)

#define MMA(hA, hB) do {                                                          \
    __builtin_amdgcn_s_setprio(1);                                                \
    _Pragma("unroll") for (int m = 0; m < MF; m++)                                \
    _Pragma("unroll") for (int n = 0; n < 2; n++)                                 \
    _Pragma("unroll") for (int ks = 0; ks < 2; ks++)                              \
        acc[hA][hB][m][n] = __builtin_amdgcn_mfma_f32_16x16x32_bf16(              \
            afr[m][ks], bfr[hB][n][ks], acc[hA][hB][m][n], 0, 0, 0);              \
    __builtin_amdgcn_s_setprio(0);                                                \
} while (0)

// BIAS_MODE: 0=none, 1=bias[col], 2=bias[row].  BIAS_SPLIT: bias1 when bz>0.
template<int BM, bool OUT_F32, bool RELU, int BIAS_MODE, bool BIAS_SPLIT>
__global__ __launch_bounds__(512, 2)
void gemm256(const bf16_t* __restrict__ A, const bf16_t* __restrict__ B,
             const float* __restrict__ bias0, const float* __restrict__ bias1,
             void* __restrict__ Cp,
             int K, int ldc, long sAb, long sBb, long sCb)
{
    constexpr int MF     = BM / 64;           // 16-row m-frags per wave per phase
    constexpr int LA     = BM / 128;          // loads per thread per A half-tile
    constexpr int VMN    = 4 + LA;            // steady-state vmcnt
    constexpr int ABYTES = BM * 128;          // A tile bytes (BM x 64 bf16)
    constexpr int HBYTES = ABYTES / 2;
    constexpr int BUF    = ABYTES + 32768;

    __shared__ char lds[2 * BUF];

    // bijective XCD-chunk swizzle (all grids here are 256 wg, %8 == 0)
    const int gx = gridDim.x, gy = gridDim.y;
    const int tot = gx * gy * gridDim.z;
    const int lin = (blockIdx.z * gy + blockIdx.y) * gx + blockIdx.x;
    const int q8  = tot >> 3;
    const int wg  = (lin & 7) * q8 + (lin >> 3);
    const int bz  = wg / (gx * gy);
    const int r2  = wg - bz * gx * gy;
    const int by  = r2 / gx;
    const int bx  = r2 - by * gx;
    const int blockM = by * BM;
    const int blockN = bx * 256;

    const int t    = threadIdx.x;
    const int lane = t & 63;
    const int wave = t >> 6;
    const int sr   = wave >> 2;         // 0..1 row group
    const int sc   = wave & 3;          // 0..3 col group
    const int l15  = lane & 15;
    const int l4   = lane >> 4;         // 0..3 k-slot group

    const bf16_t* ApM = A + sAb * (long)bz + (long)blockM * K;
    const bf16_t* BpN = B + sBb * (long)bz + (long)blockN * K;

    // staging constants: chunk c of a half-tile; row=c>>3, slot=c&7; global
    // source pre-swizzled (slot ^ row&7), LDS dest linear (c*16).
    long offA[LA]; uint32_t dstA[LA];
    #pragma unroll
    for (int j = 0; j < LA; j++) {
        const int c = t + j * 512, r = c >> 3, s = c & 7;
        offA[j] = (long)r * K + ((s ^ (r & 7)) * 8);
        dstA[j] = (uint32_t)c * 16;
    }
    long offB[2]; uint32_t dstB[2];
    #pragma unroll
    for (int j = 0; j < 2; j++) {
        const int c = t + j * 512, r = c >> 3, s = c & 7;
        offB[j] = (long)r * K + ((s ^ (r & 7)) * 8);
        dstB[j] = (uint32_t)c * 16;
    }

    f32x4  acc[2][2][MF][2] = {};
    bf16x8 afr[MF][2];
    bf16x8 bfr[2][2][2];

    const int NT = K >> 6;
    const int NI = NT >> 1;

    // prologue: buf0 tile0 {A0,B0,B1,A1}; buf1 tile1 {A0,B0,B1}.
    // vmcnt(VMN) leaves exactly the 3 tile-1 stages in flight -> tile0 landed.
    STAGEA(0, 0, 0); STAGEB(0, 0, 0); STAGEB(0, 1, 0); STAGEA(0, 1, 0);
    STAGEA(1, 0, 1); STAGEB(1, 0, 1); STAGEB(1, 1, 1);
    vmw<VMN>();
    BARR();

    for (int i = 0; i < NI; ++i) {
        const int  T  = 2 * i;
        const bool nl = (i < NI - 1);

        // p1: (buf0, A0, B0)
        LOADA(0, 0); LOADB(0, 0);
        STAGEA(1, 1, T + 1);
        BARR();
        MMA(0, 0);
        BARR();
        // p2: (buf0, A0, B1) — afr reused
        LOADB(0, 1);
        if (nl) STAGEA(0, 0, T + 2);
        BARR();
        MMA(0, 1);
        BARR();
        // p3: (buf0, A1, B0) — bfr[0] reused
        LOADA(0, 1);
        if (nl) STAGEB(0, 0, T + 2);
        BARR();
        MMA(1, 0);
        BARR();
        // p4: (buf0, A1, B1) — all frags reused; K-tile wait
        if (nl) STAGEB(0, 1, T + 2);
        BARR();
        MMA(1, 1);
        if (nl) vmw<VMN>(); else vmw<0>();
        BARR();
        // p5: (buf1, A0, B0)
        LOADA(1, 0); LOADB(1, 0);
        if (nl) STAGEA(0, 1, T + 2);
        BARR();
        MMA(0, 0);
        BARR();
        // p6: (buf1, A0, B1)
        LOADB(1, 1);
        if (nl) STAGEA(1, 0, T + 3);
        BARR();
        MMA(0, 1);
        BARR();
        // p7: (buf1, A1, B0)
        LOADA(1, 1);
        if (nl) STAGEB(1, 0, T + 3);
        BARR();
        MMA(1, 0);
        BARR();
        // p8: (buf1, A1, B1); K-tile wait
        if (nl) STAGEB(1, 1, T + 3);
        BARR();
        MMA(1, 1);
        if (nl) vmw<VMN>();
        BARR();
    }

    // epilogue: 16x16 C/D layout: col = lane&15, row = (lane>>4)*4 + reg
    float*  Cf = (float*) Cp + sCb * (long)bz;
    bf16_t* Ch = (bf16_t*)Cp + sCb * (long)bz;
    const float* bias = (BIAS_SPLIT && bz) ? bias1 : bias0;
    #pragma unroll
    for (int hA = 0; hA < 2; hA++)
    #pragma unroll
    for (int hB = 0; hB < 2; hB++)
    #pragma unroll
    for (int m = 0; m < MF; m++)
    #pragma unroll
    for (int n = 0; n < 2; n++) {
        const int gcol = blockN + hB * 128 + sc * 32 + n * 16 + l15;
        float bc = 0.f;
        if (BIAS_MODE == 1) bc = bias[gcol];
        #pragma unroll
        for (int reg = 0; reg < 4; reg++) {
            const int grow = blockM + hA * (BM / 2) + sr * (BM / 4) + m * 16
                           + l4 * 4 + reg;
            float vv = acc[hA][hB][m][n][reg];
            if (BIAS_MODE == 1) vv += bc;
            if (BIAS_MODE == 2) vv += bias[grow];
            if (RELU) vv = fmaxf(vv, 0.f);
            if (OUT_F32) Cf[(long)grow * ldc + gcol] = vv;
            else         Ch[(long)grow * ldc + gcol] = (bf16_t)vv;
        }
    }
}

// fp32 -> bf16 cast of q,k,v,Wq,Wk,Wv into workspace.
// Round-5 post-mortem: rounds 2/3/5 used three different access shapes and all
// ran ~45-48 us -> coalescing was NOT the limiter.  Round-5 VGPR_Count=8 is the
// tell: one float4 (4 VGPR) in flight, so each grid-stride iteration serializes
// load-latency + store-latency (next load reuses the store's source VGPRs and
// must wait for store retirement).  Fix:
//   (1) 8-deep MLP: U_TOT = 8 x 884736 exactly; issue all 8 independent loads
//       first (static unroll, rule-20-safe), then convert + store.
//   (2) nontemporal stores: output is write-once (consumed by later dispatches
//       from L3/HBM); bypass L2 allocation / RFO on the write stream
//       (round-5 FETCH ~= WRITE ~= 55 MB while inputs were L3-resident).
//       NOTE: __builtin_nontemporal_store rejects HIP_vector_type (uint2 is a
//       class) -> pack the 4 bf16 into a plain unsigned long long (round-7
//       compile fix; pointer-to-integer is a legal builtin operand).
// Layout per j-slice: u = tid + j*884736; j=0..6 lie wholly in q/k/v
// (7*884736 = 6193152 <= 6291456); j=7 crosses into the weights region.
__global__ __launch_bounds__(256)
void cast_all_kernel(const float* __restrict__ q, const float* __restrict__ k,
                     const float* __restrict__ v, const float* __restrict__ Wq,
                     const float* __restrict__ Wk, const float* __restrict__ Wv,
                     bf16_t* __restrict__ ws)
{
    const int NTH   = 884736;      // 3456 blocks * 256 threads
    const int BIGT  = 6291456;     // 3 * 2^21 float4 units in q/k/v
    const int tid   = blockIdx.x * blockDim.x + threadIdx.x;

    float4 a[8];
    #pragma unroll
    for (int j = 0; j < 8; ++j) {
        const int u = tid + j * NTH;
        const float* src;
        if (j < 7 || u < BIGT) {
            const int s = u >> 21;
            src = (s == 0 ? q : s == 1 ? k : v) + ((long)(u & 2097151) << 2);
        } else {
            const int u2 = u - BIGT;
            const int s  = u2 >> 18;
            src = (s == 0 ? Wq : s == 1 ? Wk : Wv) + ((long)(u2 & 262143) << 2);
        }
        a[j] = *(const float4*)src;
    }
    #pragma unroll
    for (int j = 0; j < 8; ++j) {
        const int u = tid + j * NTH;
        bf16_t* dst;
        if (j < 7 || u < BIGT) {
            const int s = u >> 21;
            dst = ws + (long)s * 8388608 + ((long)(u & 2097151) << 2);
        } else {
            const int u2 = u - BIGT;
            const int s  = u2 >> 18;
            dst = ws + 25165824L + (long)s * 1048576 + ((long)(u2 & 262143) << 2);
        }
        alignas(8) bf16_t o[4];
        o[0] = (bf16_t)a[j].x; o[1] = (bf16_t)a[j].y;
        o[2] = (bf16_t)a[j].z; o[3] = (bf16_t)a[j].w;
        __builtin_nontemporal_store(*(const unsigned long long*)o,
                                    (unsigned long long*)dst);
    }
}

extern "C" void kernel_launch(void* const* d_in, const int* in_sizes, int n_in,
                              void* d_out, int out_size, void* d_ws, size_t ws_size,
                              hipStream_t stream)
{
    const float* q   = (const float*)d_in[0];
    const float* k   = (const float*)d_in[1];
    const float* v   = (const float*)d_in[2];
    const float* Wq  = (const float*)d_in[3];
    const float* bq  = (const float*)d_in[4];
    const float* Wk  = (const float*)d_in[5];
    const float* bk  = (const float*)d_in[6];
    const float* Wv  = (const float*)d_in[7];
    const float* bv  = (const float*)d_in[8];

    const int S = 2048, D = 1024;

    // workspace (bf16 element offsets):
    //   qb 0, kb 8388608, vb 16777216 (dead after their GEMM; Sc aliases qb+kb)
    //   Wqb 25165824, Wkb 26214400, Wvb 27262976
    //   Qp 28311552, Kp 36700160, VpT 45088768   (total ~107 MB)
    bf16_t* ws  = (bf16_t*)d_ws;
    bf16_t* qb  = ws;
    bf16_t* vb  = ws + 16777216L;
    bf16_t* Wqb = ws + 25165824L;
    bf16_t* Wvb = ws + 27262976L;
    bf16_t* Qp  = ws + 28311552L;
    bf16_t* VpT = ws + 45088768L;
    bf16_t* Sc  = ws;              // aliases qb+kb (both dead by step 4)

    cast_all_kernel<<<dim3(3456), dim3(256), 0, stream>>>(q, k, v, Wq, Wk, Wv, ws);

    dim3 blk(512);

    // Q and K projections fused via grid.z (qb/kb, Wqb/Wkb, Qp/Kp contiguous):
    // [M=8192, N=1024, K=1024] x2 -> grid (4,32,2) = 256 wg
    gemm256<256, false, false, 1, true><<<dim3(4, 32, 2), blk, 0, stream>>>(
        qb, Wqb, bq, bk, Qp, D, D, 8388608L, 1048576L, 8388608L);

    // VpT[b] = (v_b @ Wv^T + bv)^T : A=Wvb [1024,1024], B=vb_b [2048,1024],
    // row bias.  BM=128 -> grid (8,8,4) = 256 wg
    gemm256<128, false, false, 2, false><<<dim3(8, 8, 4), blk, 0, stream>>>(
        Wvb, vb, bv, nullptr, VpT, D, S, 0L, (long)S * D, (long)D * S);

    // Sc[b] = relu(Qp_b @ Kp_b^T)  [2048x2048, K=1024], bf16 out -> (8,8,4)=256 wg
    gemm256<256, false, true, 0, false><<<dim3(8, 8, 4), blk, 0, stream>>>(
        Qp, Qp + 8388608L, nullptr, nullptr, Sc, D, S,
        (long)S * D, (long)S * D, (long)S * S);

    // out[b] = Sc_b @ VpT_b^T  [2048x1024, K=2048], fp32 out.
    // BM=128 -> grid (4,16,4) = 256 wg
    gemm256<128, true, false, 0, false><<<dim3(4, 16, 4), blk, 0, stream>>>(
        Sc, VpT, nullptr, nullptr, d_out, S, D,
        (long)S * S, (long)D * S, (long)S * D);
}

// Round 14
// 281.649 us; speedup vs baseline: 1.0196x; 1.0118x over previous
//
#include <hip/hip_runtime.h>
#include <hip/hip_bf16.h>
#include <stdint.h>

typedef __bf16 bf16_t;
typedef __bf16 bf16x8 __attribute__((ext_vector_type(8)));
typedef float  f32x4  __attribute__((ext_vector_type(4)));

// async 16B global -> LDS (global_load_lds_dwordx4).
__device__ __forceinline__ void async_copy16(const bf16_t* g, bf16_t* l) {
    __builtin_amdgcn_global_load_lds(
        (const __attribute__((address_space(1))) unsigned int*)(uintptr_t)g,
        (__attribute__((address_space(3))) unsigned int*)(uintptr_t)l,
        16, 0, 0);
}

// Counted vmcnt wait. NO memory clobber: a "memory" clobber makes the asm an
// opaque memory op and SIInsertWaitcnts prepends s_waitcnt vmcnt(0) to it,
// which silently degrades the whole schedule to drain-per-phase (round-1 bug).
template<int N> __device__ __forceinline__ void vmw() {
    if constexpr (N == 0)      asm volatile("s_waitcnt vmcnt(0)");
    else if constexpr (N == 5) asm volatile("s_waitcnt vmcnt(5)");
    else if constexpr (N == 6) asm volatile("s_waitcnt vmcnt(6)");
}
#define BARR() __builtin_amdgcn_s_barrier()

// ---------------------------------------------------------------------------
// BMx256 8-phase NT GEMM, bf16 in, fp32 acc: C[m,n] = op(sum_k A[m,k]*B[n,k]+bias)
// 512 thr = 8 waves (2 row-groups x 4 col-groups). Phase = one (BM/2)x128
// C-region over a K=64 tile: per wave (BM/64) x 2 frags of 16x16 x 2 ksteps ->
// 4*(BM/64) x mfma_f32_16x16x32_bf16 (16 for BM=256, 8 for BM=128).
//
// NOTE fragment shape: 16x16 (l15-row reads), NOT 32x32 (r32-row reads).
// Empirical across rounds 0/1/2: r32-pattern ds_read_b128 = 4.19M bank-conflict
// cycles/dispatch; l15-pattern = 0.  Same slot-XOR swizzle in both.
//
// LDS: 2 buf x (A[BM][64] + B[256][64]) bf16 = 128 KiB (BM=256) / 96 KiB (128).
//
// Stage ledger (1 half-tile per phase; T = 2i; A-half = LA loads, B-half = 2):
//   p1: A1(T+1)->buf1   p2: A0(T+2)->buf0   p3: B0(T+2)->buf0  p4: B1(T+2)->buf0
//   p5: A1(T+2)->buf0   p6: A0(T+3)->buf1   p7: B0(T+3)->buf1  p8: B1(T+3)->buf1
// Reads: p1:{A0,B0} p2:{B1} p3:{A1} p4:{} of buf0/T; p5..p8 same of buf1/T+1.
// vmcnt(4+LA) after MMA at p4 and p8 only (3 stages in flight):
//   p4 wait covers <= p1 -> buf1 tile 2i+1 fully landed (prev p6,p7,p8 + p1).
//   p8 wait covers <= p5 -> buf0 tile 2i+2 fully landed (p2,p3,p4,p5).
// Write-safety: every stage overwrites a half-tile whose last ds_read was >=1
// barrier earlier, and those reads are consumed by same-phase MFMAs (dataflow
// lgkmcnt) before that barrier.  Last iter: skip p2..p8 stages, p4 -> vmcnt(0).
// ---------------------------------------------------------------------------

#define STAGEA(buf, h, kt) do {                                                   \
    _Pragma("unroll") for (int j = 0; j < LA; j++)                                \
        async_copy16(ApM + (long)(h)*(BM/2)*K + (long)(kt)*64 + offA[j],          \
                     (bf16_t*)(lds + (buf)*BUF + (h)*HBYTES + dstA[j]));          \
} while (0)

#define STAGEB(buf, h, kt) do {                                                   \
    _Pragma("unroll") for (int j = 0; j < 2; j++)                                 \
        async_copy16(BpN + (long)(h)*128*K + (long)(kt)*64 + offB[j],             \
                     (bf16_t*)(lds + (buf)*BUF + ABYTES + (h)*16384 + dstB[j]));  \
} while (0)

// 16x16x32 frags: row/col = l15, k = ks*32 + l4*8 + 0..7 -> 16B slot ks*4+l4,
// stored (and read) at slot ^ (row&7): same involution on both sides (stage
// pre-swizzles the GLOBAL source, LDS dest stays linear).
#define LOADA(buf, hA) do {                                                       \
    _Pragma("unroll") for (int m = 0; m < MF; m++)                                \
    _Pragma("unroll") for (int ks = 0; ks < 2; ks++) {                            \
        const int R = (hA)*(BM/2) + sr*(BM/4) + m*16 + l15;                       \
        afr[m][ks] = *(const bf16x8*)(lds + (buf)*BUF + R*128                     \
                                      + (((ks*4 + l4) ^ (l15 & 7)) << 4));        \
    } } while (0)

#define LOADB(buf, hB) do {                                                       \
    _Pragma("unroll") for (int n = 0; n < 2; n++)                                 \
    _Pragma("unroll") for (int ks = 0; ks < 2; ks++) {                            \
        const int Cc = (hB)*128 + sc*32 + n*16 + l15;                             \
        bfr[hB][n][ks] = *(const bf16x8*)(lds + (buf)*BUF + ABYTES + Cc*128       \
                                          + (((ks*4 + l4) ^ (l15 & 7)) << 4));    \
    } } while (0)

#define MMA(hA, hB) do {                                                          \
    __builtin_amdgcn_s_setprio(1);                                                \
    _Pragma("unroll") for (int m = 0; m < MF; m++)                                \
    _Pragma("unroll") for (int n = 0; n < 2; n++)                                 \
    _Pragma("unroll") for (int ks = 0; ks < 2; ks++)                              \
        acc[hA][hB][m][n] = __builtin_amdgcn_mfma_f32_16x16x32_bf16(              \
            afr[m][ks], bfr[hB][n][ks], acc[hA][hB][m][n], 0, 0, 0);              \
    __builtin_amdgcn_s_setprio(0);                                                \
} while (0)

// BIAS_MODE: 0=none, 1=bias[col], 2=bias[row].  BIAS_SPLIT: bias1 when bz>0.
template<int BM, bool OUT_F32, bool RELU, int BIAS_MODE, bool BIAS_SPLIT>
__global__ __launch_bounds__(512, 2)
void gemm256(const bf16_t* __restrict__ A, const bf16_t* __restrict__ B,
             const float* __restrict__ bias0, const float* __restrict__ bias1,
             void* __restrict__ Cp,
             int K, int ldc, long sAb, long sBb, long sCb)
{
    constexpr int MF     = BM / 64;           // 16-row m-frags per wave per phase
    constexpr int LA     = BM / 128;          // loads per thread per A half-tile
    constexpr int VMN    = 4 + LA;            // steady-state vmcnt
    constexpr int ABYTES = BM * 128;          // A tile bytes (BM x 64 bf16)
    constexpr int HBYTES = ABYTES / 2;
    constexpr int BUF    = ABYTES + 32768;

    __shared__ char lds[2 * BUF];

    // bijective XCD-chunk swizzle (all grids here are 256 wg, %8 == 0)
    const int gx = gridDim.x, gy = gridDim.y;
    const int tot = gx * gy * gridDim.z;
    const int lin = (blockIdx.z * gy + blockIdx.y) * gx + blockIdx.x;
    const int q8  = tot >> 3;
    const int wg  = (lin & 7) * q8 + (lin >> 3);
    const int bz  = wg / (gx * gy);
    const int r2  = wg - bz * gx * gy;
    const int by  = r2 / gx;
    const int bx  = r2 - by * gx;
    const int blockM = by * BM;
    const int blockN = bx * 256;

    const int t    = threadIdx.x;
    const int lane = t & 63;
    const int wave = t >> 6;
    const int sr   = wave >> 2;         // 0..1 row group
    const int sc   = wave & 3;          // 0..3 col group
    const int l15  = lane & 15;
    const int l4   = lane >> 4;         // 0..3 k-slot group

    const bf16_t* ApM = A + sAb * (long)bz + (long)blockM * K;
    const bf16_t* BpN = B + sBb * (long)bz + (long)blockN * K;

    // staging constants: chunk c of a half-tile; row=c>>3, slot=c&7; global
    // source pre-swizzled (slot ^ row&7), LDS dest linear (c*16).
    long offA[LA]; uint32_t dstA[LA];
    #pragma unroll
    for (int j = 0; j < LA; j++) {
        const int c = t + j * 512, r = c >> 3, s = c & 7;
        offA[j] = (long)r * K + ((s ^ (r & 7)) * 8);
        dstA[j] = (uint32_t)c * 16;
    }
    long offB[2]; uint32_t dstB[2];
    #pragma unroll
    for (int j = 0; j < 2; j++) {
        const int c = t + j * 512, r = c >> 3, s = c & 7;
        offB[j] = (long)r * K + ((s ^ (r & 7)) * 8);
        dstB[j] = (uint32_t)c * 16;
    }

    f32x4  acc[2][2][MF][2] = {};
    bf16x8 afr[MF][2];
    bf16x8 bfr[2][2][2];

    const int NT = K >> 6;
    const int NI = NT >> 1;

    // prologue: buf0 tile0 {A0,B0,B1,A1}; buf1 tile1 {A0,B0,B1}.
    // vmcnt(VMN) leaves exactly the 3 tile-1 stages in flight -> tile0 landed.
    STAGEA(0, 0, 0); STAGEB(0, 0, 0); STAGEB(0, 1, 0); STAGEA(0, 1, 0);
    STAGEA(1, 0, 1); STAGEB(1, 0, 1); STAGEB(1, 1, 1);
    vmw<VMN>();
    BARR();

    for (int i = 0; i < NI; ++i) {
        const int  T  = 2 * i;
        const bool nl = (i < NI - 1);

        // p1: (buf0, A0, B0)
        LOADA(0, 0); LOADB(0, 0);
        STAGEA(1, 1, T + 1);
        BARR();
        MMA(0, 0);
        BARR();
        // p2: (buf0, A0, B1) — afr reused
        LOADB(0, 1);
        if (nl) STAGEA(0, 0, T + 2);
        BARR();
        MMA(0, 1);
        BARR();
        // p3: (buf0, A1, B0) — bfr[0] reused
        LOADA(0, 1);
        if (nl) STAGEB(0, 0, T + 2);
        BARR();
        MMA(1, 0);
        BARR();
        // p4: (buf0, A1, B1) — all frags reused; K-tile wait
        if (nl) STAGEB(0, 1, T + 2);
        BARR();
        MMA(1, 1);
        if (nl) vmw<VMN>(); else vmw<0>();
        BARR();
        // p5: (buf1, A0, B0)
        LOADA(1, 0); LOADB(1, 0);
        if (nl) STAGEA(0, 1, T + 2);
        BARR();
        MMA(0, 0);
        BARR();
        // p6: (buf1, A0, B1)
        LOADB(1, 1);
        if (nl) STAGEA(1, 0, T + 3);
        BARR();
        MMA(0, 1);
        BARR();
        // p7: (buf1, A1, B0)
        LOADA(1, 1);
        if (nl) STAGEB(1, 0, T + 3);
        BARR();
        MMA(1, 0);
        BARR();
        // p8: (buf1, A1, B1); K-tile wait
        if (nl) STAGEB(1, 1, T + 3);
        BARR();
        MMA(1, 1);
        if (nl) vmw<VMN>();
        BARR();
    }

    // epilogue: 16x16 C/D layout: col = lane&15, row = (lane>>4)*4 + reg
    float*  Cf = (float*) Cp + sCb * (long)bz;
    bf16_t* Ch = (bf16_t*)Cp + sCb * (long)bz;
    const float* bias = (BIAS_SPLIT && bz) ? bias1 : bias0;
    #pragma unroll
    for (int hA = 0; hA < 2; hA++)
    #pragma unroll
    for (int hB = 0; hB < 2; hB++)
    #pragma unroll
    for (int m = 0; m < MF; m++)
    #pragma unroll
    for (int n = 0; n < 2; n++) {
        const int gcol = blockN + hB * 128 + sc * 32 + n * 16 + l15;
        float bc = 0.f;
        if (BIAS_MODE == 1) bc = bias[gcol];
        #pragma unroll
        for (int reg = 0; reg < 4; reg++) {
            const int grow = blockM + hA * (BM / 2) + sr * (BM / 4) + m * 16
                           + l4 * 4 + reg;
            float vv = acc[hA][hB][m][n][reg];
            if (BIAS_MODE == 1) vv += bc;
            if (BIAS_MODE == 2) vv += bias[grow];
            if (RELU) vv = fmaxf(vv, 0.f);
            if (OUT_F32) Cf[(long)grow * ldc + gcol] = vv;
            else         Ch[(long)grow * ldc + gcol] = (bf16_t)vv;
        }
    }
}

// fp32 -> bf16 cast of q,k,v,Wq,Wk,Wv into workspace.
// History: five access shapes (48B one-shot / 64B chunks / float4-per-lane /
// "8-deep" unroll / +NT stores) all measured 45-48 us.  Round-9 VGPR_Count=28
// (< 32 needed for 8 live float4) proves the compiler COLLAPSED the 8-deep
// load batch back into a shallow load->store interleave (machine scheduler
// sinks each store to just after its load to save registers) -> the deep-MLP
// schedule was never actually emitted.  This round: force it with
// __builtin_amdgcn_sched_barrier(0) between the load loop and the store loop
// (hard scheduling-region boundary; loads cannot be crossed by stores).
// Pre-committed read: VGPR>=44 & dur ~30us -> MLP confirmed; VGPR>=44 & dur
// ~47us -> source-level shapes exhausted, next round eliminates the cast by
// fusing fp32 staging into the projection GEMMs.
// Layout per j-slice: u = tid + j*884736; j=0..6 lie wholly in q/k/v
// (7*884736 = 6193152 <= 6291456); j=7 crosses into the weights region.
__global__ __launch_bounds__(256)
void cast_all_kernel(const float* __restrict__ q, const float* __restrict__ k,
                     const float* __restrict__ v, const float* __restrict__ Wq,
                     const float* __restrict__ Wk, const float* __restrict__ Wv,
                     bf16_t* __restrict__ ws)
{
    const int NTH   = 884736;      // 3456 blocks * 256 threads
    const int BIGT  = 6291456;     // 3 * 2^21 float4 units in q/k/v
    const int tid   = blockIdx.x * blockDim.x + threadIdx.x;

    float4 a[8];
    #pragma unroll
    for (int j = 0; j < 8; ++j) {
        const int u = tid + j * NTH;
        const float* src;
        if (j < 7 || u < BIGT) {
            const int s = u >> 21;
            src = (s == 0 ? q : s == 1 ? k : v) + ((long)(u & 2097151) << 2);
        } else {
            const int u2 = u - BIGT;
            const int s  = u2 >> 18;
            src = (s == 0 ? Wq : s == 1 ? Wk : Wv) + ((long)(u2 & 262143) << 2);
        }
        a[j] = *(const float4*)src;
    }
    // Hard scheduling fence: all 8 global_load_dwordx4 must be ISSUED before
    // any dependent convert/store is scheduled -> true 8-deep MLP per thread.
    __builtin_amdgcn_sched_barrier(0);
    #pragma unroll
    for (int j = 0; j < 8; ++j) {
        const int u = tid + j * NTH;
        bf16_t* dst;
        if (j < 7 || u < BIGT) {
            const int s = u >> 21;
            dst = ws + (long)s * 8388608 + ((long)(u & 2097151) << 2);
        } else {
            const int u2 = u - BIGT;
            const int s  = u2 >> 18;
            dst = ws + 25165824L + (long)s * 1048576 + ((long)(u2 & 262143) << 2);
        }
        alignas(8) bf16_t o[4];
        o[0] = (bf16_t)a[j].x; o[1] = (bf16_t)a[j].y;
        o[2] = (bf16_t)a[j].z; o[3] = (bf16_t)a[j].w;
        __builtin_nontemporal_store(*(const unsigned long long*)o,
                                    (unsigned long long*)dst);
    }
}

extern "C" void kernel_launch(void* const* d_in, const int* in_sizes, int n_in,
                              void* d_out, int out_size, void* d_ws, size_t ws_size,
                              hipStream_t stream)
{
    const float* q   = (const float*)d_in[0];
    const float* k   = (const float*)d_in[1];
    const float* v   = (const float*)d_in[2];
    const float* Wq  = (const float*)d_in[3];
    const float* bq  = (const float*)d_in[4];
    const float* Wk  = (const float*)d_in[5];
    const float* bk  = (const float*)d_in[6];
    const float* Wv  = (const float*)d_in[7];
    const float* bv  = (const float*)d_in[8];

    const int S = 2048, D = 1024;

    // workspace (bf16 element offsets):
    //   qb 0, kb 8388608, vb 16777216 (dead after their GEMM; Sc aliases qb+kb)
    //   Wqb 25165824, Wkb 26214400, Wvb 27262976
    //   Qp 28311552, Kp 36700160, VpT 45088768   (total ~107 MB)
    bf16_t* ws  = (bf16_t*)d_ws;
    bf16_t* qb  = ws;
    bf16_t* vb  = ws + 16777216L;
    bf16_t* Wqb = ws + 25165824L;
    bf16_t* Wvb = ws + 27262976L;
    bf16_t* Qp  = ws + 28311552L;
    bf16_t* VpT = ws + 45088768L;
    bf16_t* Sc  = ws;              // aliases qb+kb (both dead by step 4)

    cast_all_kernel<<<dim3(3456), dim3(256), 0, stream>>>(q, k, v, Wq, Wk, Wv, ws);

    dim3 blk(512);

    // Q and K projections fused via grid.z (qb/kb, Wqb/Wkb, Qp/Kp contiguous):
    // [M=8192, N=1024, K=1024] x2 -> grid (4,32,2) = 256 wg
    gemm256<256, false, false, 1, true><<<dim3(4, 32, 2), blk, 0, stream>>>(
        qb, Wqb, bq, bk, Qp, D, D, 8388608L, 1048576L, 8388608L);

    // VpT[b] = (v_b @ Wv^T + bv)^T : A=Wvb [1024,1024], B=vb_b [2048,1024],
    // row bias.  BM=128 -> grid (8,8,4) = 256 wg
    gemm256<128, false, false, 2, false><<<dim3(8, 8, 4), blk, 0, stream>>>(
        Wvb, vb, bv, nullptr, VpT, D, S, 0L, (long)S * D, (long)D * S);

    // Sc[b] = relu(Qp_b @ Kp_b^T)  [2048x2048, K=1024], bf16 out -> (8,8,4)=256 wg
    gemm256<256, false, true, 0, false><<<dim3(8, 8, 4), blk, 0, stream>>>(
        Qp, Qp + 8388608L, nullptr, nullptr, Sc, D, S,
        (long)S * D, (long)S * D, (long)S * S);

    // out[b] = Sc_b @ VpT_b^T  [2048x1024, K=2048], fp32 out.
    // BM=128 -> grid (4,16,4) = 256 wg
    gemm256<128, true, false, 0, false><<<dim3(4, 16, 4), blk, 0, stream>>>(
        Sc, VpT, nullptr, nullptr, d_out, S, D,
        (long)S * S, (long)D * S, (long)S * D);
}